// Round 1
// baseline (18634.497 us; speedup 1.0000x reference)
//
#include <hip/hip_runtime.h>
#include <hip/hip_fp16.h>

// Problem constants
#define L_SEQ 576
#define BATCH 16
#define HIDDEN 800
#define G4 3200
#define NT 200      // N tiles per direction (3200/16)
#define KQ_HH 25    // K chunks for W_hh (800/32)
#define KQ_L1 50    // 1600/32
#define KQ_L0 2     // padded 64/32

typedef _Float16 h8 __attribute__((ext_vector_type(8)));
typedef _Float16 h4 __attribute__((ext_vector_type(4)));
typedef float f4 __attribute__((ext_vector_type(4)));

__device__ __forceinline__ float sigmoidf_(float x){
  x = fminf(30.f, fmaxf(-30.f, x));
  return 1.f/(1.f+__expf(-x));
}
__device__ __forceinline__ float tanhf_(float x){
  x = fminf(15.f, fmaxf(-15.f, x));
  float e = __expf(2.f*x);
  return (e-1.f)/(e+1.f);
}

// ---------------- init: zero the zero-hidden buffer + barrier ----------------
__global__ void init_kernel(_Float16* zbuf, int* bar){
  int i = blockIdx.x*256 + threadIdx.x;
  if(i < BATCH*1600) zbuf[i] = (_Float16)0.f;
  if(i == 0){ bar[0] = 0; bar[1] = 0; }
}

// ---------------- build x (L*B, 64) f16: [onehot(20) | pssm(21) | pad0] -----
__global__ void build_x(const int* __restrict__ seq, const float* __restrict__ pssm,
                        _Float16* __restrict__ x){
  int i = blockIdx.x*256 + threadIdx.x;
  if(i >= L_SEQ*BATCH*64) return;
  int m = i >> 6, k = i & 63;
  float v = 0.f;
  if(k < 20)      v = (seq[m]==k) ? 1.f : 0.f;
  else if(k < 41) v = pssm[m*21 + (k-20)];
  x[i] = (_Float16)v;
}

// ---------------- weight prep: fp32 -> f16 MFMA B-fragment layout ------------
// B-frag: lane l holds B[k=q*32+(l>>4)*8+j][n = tile*16 + (l&15)], j=0..7
// n-permutation: col c=l&15 -> unit u = T*4 + (c>>2), gate g = c&3, W row = g*800+u
__global__ void prep_w(
  const float* __restrict__ whh0f, const float* __restrict__ whh0b,
  const float* __restrict__ whh1f, const float* __restrict__ whh1b,
  const float* __restrict__ wih1f, const float* __restrict__ wih1b,
  const float* __restrict__ wih0f, const float* __restrict__ wih0b,
  h8* __restrict__ wp_hh, h8* __restrict__ wp1, h8* __restrict__ wp0)
{
  long idx = (long)blockIdx.x*256 + threadIdx.x;
  const long J1 = 4L*320000, J2 = 2L*640000, J3 = 2L*25600;
  if(idx < J1){
    int d = (int)(idx/320000); int r = (int)(idx%320000);
    int T = r/1600, q = (r%1600)/64, l = r&63;
    const float* W = (d==0)?whh0f:(d==1)?whh0b:(d==2)?whh1f:whh1b;
    int c = l&15; int n = (c&3)*800 + T*4 + (c>>2);
    const float* src = W + (size_t)n*800 + q*32 + ((l>>4)<<3);
    h8 v;
    #pragma unroll
    for(int j=0;j<8;++j) v[j] = (_Float16)src[j];
    wp_hh[idx] = v;
  } else if(idx < J1+J2){
    long i2 = idx - J1;
    int d = (int)(i2/640000); int r = (int)(i2%640000);
    int T = r/3200, q = (r%3200)/64, l = r&63;
    const float* W = d ? wih1b : wih1f;
    int c = l&15; int n = (c&3)*800 + T*4 + (c>>2);
    const float* src = W + (size_t)n*1600 + q*32 + ((l>>4)<<3);
    h8 v;
    #pragma unroll
    for(int j=0;j<8;++j) v[j] = (_Float16)src[j];
    wp1[i2] = v;
  } else if(idx < J1+J2+J3){
    long i3 = idx - J1 - J2;
    int d = (int)(i3/25600); int r = (int)(i3%25600);
    int T = r/128, q = (r%128)/64, l = r&63;
    const float* W = d ? wih0b : wih0f;
    int c = l&15; int n = (c&3)*800 + T*4 + (c>>2);
    int k0 = q*32 + ((l>>4)<<3);
    h8 v;
    #pragma unroll
    for(int j=0;j<8;++j){ int k = k0+j; v[j] = (_Float16)((k<41)? W[(size_t)n*41+k] : 0.f); }
    wp0[i3] = v;
  }
}

// ------------- input-projection GEMM -> permuted Gp layout (f16) -------------
// Gp[((t*200+T)*64+l)*4 + r] = G[t][b=(l>>4)*4+r][n(T, c=l&15)]   (bias included)
__global__ __launch_bounds__(256) void gemm_gp(
  const _Float16* __restrict__ A, int lda, int KQ,
  const h8* __restrict__ WpF, const h8* __restrict__ WpB,
  const float* __restrict__ bihF, const float* __restrict__ bhhF,
  const float* __restrict__ bihB, const float* __restrict__ bhhB,
  _Float16* __restrict__ GpF, _Float16* __restrict__ GpB)
{
  const int wv = threadIdx.x >> 6;
  const int l  = threadIdx.x & 63;
  const int mg = blockIdx.x % 144;
  const int tg = blockIdx.x / 144;       // 0..99
  const int mt = mg*4 + wv;              // 0..575  (one timestep = 16 rows)
  const int dir = tg / 50;
  const int Tb  = (tg % 50) * 4;
  const h8* Wp = dir ? WpB : WpF;
  const float* bih = dir ? bihB : bihF;
  const float* bhh = dir ? bhhB : bhhF;
  _Float16* Gp = dir ? GpB : GpF;

  const _Float16* ab = A + (size_t)(mt*16 + (l&15))*lda + ((l>>4)<<3);
  f4 acc[4] = {{0.f,0.f,0.f,0.f},{0.f,0.f,0.f,0.f},{0.f,0.f,0.f,0.f},{0.f,0.f,0.f,0.f}};
  for(int q=0;q<KQ;++q){
    h8 av = *(const h8*)(ab + q*32);
    #pragma unroll
    for(int j=0;j<4;++j){
      h8 bv = Wp[((size_t)(Tb+j)*KQ + q)*64 + l];
      acc[j] = __builtin_amdgcn_mfma_f32_16x16x32_f16(av, bv, acc[j], 0, 0, 0);
    }
  }
  const int c = l & 15;
  #pragma unroll
  for(int j=0;j<4;++j){
    int T = Tb + j;
    int n = (c&3)*800 + T*4 + (c>>2);
    float bias = bih[n] + bhh[n];
    h4 o;
    o[0]=(_Float16)(acc[j][0]+bias); o[1]=(_Float16)(acc[j][1]+bias);
    o[2]=(_Float16)(acc[j][2]+bias); o[3]=(_Float16)(acc[j][3]+bias);
    *(h4*)(Gp + (((size_t)mt*NT + T)*64 + l)*4) = o;
  }
}

// ---------------- persistent LSTM layer (both directions) -------------------
__device__ __forceinline__ void grid_barrier(int* bar, int nblk, int target){
  __syncthreads();
  if(threadIdx.x == 0){
    __threadfence();
    int prev = __hip_atomic_fetch_add(&bar[0], 1, __ATOMIC_ACQ_REL, __HIP_MEMORY_SCOPE_AGENT);
    if(prev == nblk-1){
      __hip_atomic_store(&bar[0], 0, __ATOMIC_RELAXED, __HIP_MEMORY_SCOPE_AGENT);
      __hip_atomic_store(&bar[1], target, __ATOMIC_RELEASE, __HIP_MEMORY_SCOPE_AGENT);
    } else {
      while(__hip_atomic_load(&bar[1], __ATOMIC_ACQUIRE, __HIP_MEMORY_SCOPE_AGENT) < target){
        __builtin_amdgcn_s_sleep(1);
      }
    }
    __threadfence();
  }
  __syncthreads();
}

// 100 blocks x 256 threads, no LDS -> guaranteed co-resident on 256 CUs.
// blocks 0..49 forward, 50..99 backward; each wave owns one 16-col gate tile
// (4 hidden units x 4 gates interleaved), W_hh fragments resident in VGPRs.
__global__ __launch_bounds__(256,1) void lstm_kernel(
  const h8* __restrict__ WpF, const h8* __restrict__ WpB,
  const _Float16* __restrict__ GpF, const _Float16* __restrict__ GpB,
  _Float16* __restrict__ h, const _Float16* __restrict__ zbuf,
  int* bar, int gen_base)
{
  const int wv = threadIdx.x >> 6;
  const int l  = threadIdx.x & 63;
  const int blk = blockIdx.x;
  const bool bwd = blk >= 50;
  const int T = ((bwd ? blk-50 : blk) << 2) + wv;   // 0..199
  const h8* Wp = bwd ? WpB : WpF;
  const _Float16* Gp = bwd ? GpB : GpF;
  const int col_off = bwd ? HIDDEN : 0;

  h8 Bf[KQ_HH];
  #pragma unroll
  for(int q=0;q<KQ_HH;++q) Bf[q] = Wp[(T*KQ_HH + q)*64 + l];

  float cs[4] = {0.f,0.f,0.f,0.f};
  const int m  = l & 15;
  const int kg = l >> 4;
  const int a_off = m*1600 + col_off + (kg<<3);
  const int lb = l & ~3;

  for(int s=0; s<L_SEQ; ++s){
    const int t = bwd ? (L_SEQ-1-s) : s;
    const _Float16* hp = (s==0) ? zbuf : (h + (size_t)(bwd ? (t+1) : (t-1))*(BATCH*1600));
    const _Float16* ab = hp + a_off;
    h8 a[KQ_HH];
    #pragma unroll
    for(int q=0;q<KQ_HH;++q) a[q] = *(const h8*)(ab + q*32);

    h4 gp4 = *(const h4*)(Gp + (((size_t)t*NT + T)*64 + l)*4);
    f4 acc0, acc1;
    acc0[0]=(float)gp4[0]; acc0[1]=(float)gp4[1]; acc0[2]=(float)gp4[2]; acc0[3]=(float)gp4[3];
    acc1[0]=0.f; acc1[1]=0.f; acc1[2]=0.f; acc1[3]=0.f;
    #pragma unroll
    for(int q=0;q<KQ_HH;++q){
      if(q & 1) acc1 = __builtin_amdgcn_mfma_f32_16x16x32_f16(a[q], Bf[q], acc1, 0,0,0);
      else      acc0 = __builtin_amdgcn_mfma_f32_16x16x32_f16(a[q], Bf[q], acc0, 0,0,0);
    }
    f4 g = acc0 + acc1;

    float hv[4];
    #pragma unroll
    for(int r=0;r<4;++r){
      float iv = __shfl(g[r], lb+0, 64);
      float fv = __shfl(g[r], lb+1, 64);
      float gv = __shfl(g[r], lb+2, 64);
      float ov = __shfl(g[r], lb+3, 64);
      float cn = sigmoidf_(fv)*cs[r] + sigmoidf_(iv)*tanhf_(gv);
      cs[r] = cn;
      hv[r] = sigmoidf_(ov)*tanhf_(cn);
    }
    if((l & 3) == 0){
      const int u = T*4 + (m >> 2);
      _Float16* hw = h + (size_t)t*(BATCH*1600) + col_off + u;
      #pragma unroll
      for(int r=0;r<4;++r) hw[(kg*4+r)*1600] = (_Float16)hv[r];
    }
    if(s != L_SEQ-1) grid_barrier(bar, 100, gen_base + s + 1);
  }
}

// ---------------- head: fc -> softmax-free atan2 -> SRF ---------------------
__global__ void head_kernel(const _Float16* __restrict__ h1,
                            const float* __restrict__ fcw, const float* __restrict__ fcb,
                            const float* __restrict__ alphabet,
                            const float* __restrict__ bl, const float* __restrict__ ba,
                            float* __restrict__ srf)
{
  __shared__ _Float16 sh[16*1608];   // padded stride: 804 words % 32 = 4 -> conflict-free
  __shared__ float slog[960];
  __shared__ float smax[16];
  __shared__ float sphi[48];
  const int t = blockIdx.x, tid = threadIdx.x;
  const h4* src4 = (const h4*)(h1 + (size_t)t*25600);
  h4* dst4 = (h4*)sh;
  for(int i=tid; i<6400; i+=256){
    int m = i/400, k = i%400;
    dst4[m*402 + k] = src4[i];
  }
  __syncthreads();
  for(int it=tid; it<960; it+=256){
    int j = it >> 4, b = it & 15;
    float acc = fcb[j];
    const float4* wr = (const float4*)(fcw + (size_t)j*1600);
    const h4* hr = (const h4*)(sh + b*1608);
    for(int k=0;k<400;++k){
      float4 wv = wr[k]; h4 hv = hr[k];
      acc += wv.x*(float)hv[0] + wv.y*(float)hv[1] + wv.z*(float)hv[2] + wv.w*(float)hv[3];
    }
    slog[b*60 + j] = acc;
  }
  __syncthreads();
  if(tid < 16){
    float mx = -1e30f;
    for(int j=0;j<60;++j) mx = fmaxf(mx, slog[tid*60+j]);
    smax[tid] = mx;
  }
  __syncthreads();
  if(tid < 48){
    int b = tid/3, ax = tid%3;
    float s=0.f, c=0.f, mx = smax[b];
    for(int j=0;j<60;++j){
      float e = __expf(slog[b*60+j] - mx);
      float al = alphabet[j*3 + ax];
      s += e*__sinf(al); c += e*__cosf(al);
    }
    sphi[b*3+ax] = atan2f(s, c);   // softmax denominator cancels in atan2
  }
  __syncthreads();
  if(tid < 144){
    int jj = tid/48; int r_ = tid%48; int b = r_/3, ax = r_%3;
    float rr = bl[jj], th = ba[jj], ph = sphi[b*3+jj];
    float v = (ax==0) ? rr*__cosf(th)
            : (ax==1) ? rr*__cosf(ph)*__sinf(th)
                      : rr*__sinf(ph)*__sinf(th);
    srf[(((size_t)(3*t+jj))*16 + b)*3 + ax] = v;
  }
}

// ---------------- pNeRF: 384 chain scans + 23 fragment stitches -------------
__device__ __forceinline__ void frame_cols(
  float ax,float ay,float az, float bx,float by,float bz, float cx,float cy,float cz,
  float* R)
{
  float ux=cx-bx, uy=cy-by, uz=cz-bz;
  float ir = rsqrtf(ux*ux+uy*uy+uz*uz);
  float bcx=ux*ir, bcy=uy*ir, bcz=uz*ir;
  float px=bx-ax, py=by-ay, pz=bz-az;
  float nx=py*bcz-pz*bcy, ny=pz*bcx-px*bcz, nz=px*bcy-py*bcx;
  float in_ = rsqrtf(nx*nx+ny*ny+nz*nz);
  nx*=in_; ny*=in_; nz*=in_;
  float mx=ny*bcz-nz*bcy, my=nz*bcx-nx*bcz, mz=nx*bcy-ny*bcx;
  R[0]=bcx;R[1]=bcy;R[2]=bcz; R[3]=mx;R[4]=my;R[5]=mz; R[6]=nx;R[7]=ny;R[8]=nz;
}

__global__ void pnerf_kernel(const float* __restrict__ srf,
                             float* __restrict__ frag, float* __restrict__ out)
{
  __shared__ float tail[3][16][3];
  __shared__ float sR[16][9];
  __shared__ float sorg[16][3];
  const int tid = threadIdx.x;
  if(tid < 384){
    int k = tid >> 4, b = tid & 15;
    float ax=-0.70710678f, ay=1.22474487f, az=0.f;
    float bx=-1.41421356f, by=0.f, bz=0.f;
    float cx=0.f, cy=0.f, cz=0.f;
    for(int f=0; f<72; ++f){
      const float* ct = srf + (((size_t)(k*72+f))*16 + b)*3;
      float t0=ct[0], t1=ct[1], t2=ct[2];
      float R[9];
      frame_cols(ax,ay,az, bx,by,bz, cx,cy,cz, R);
      float dx = cx + R[0]*t0 + R[3]*t1 + R[6]*t2;
      float dy = cy + R[1]*t0 + R[4]*t1 + R[7]*t2;
      float dz = cz + R[2]*t0 + R[5]*t1 + R[8]*t2;
      float* fr = frag + (((size_t)(f*24+k))*16 + b)*3;
      fr[0]=dx; fr[1]=dy; fr[2]=dz;
      if(k == 0){
        float* o = out + ((size_t)(f*16)+b)*3;
        o[0]=dx; o[1]=dy; o[2]=dz;
        if(f >= 69){ tail[f-69][b][0]=dx; tail[f-69][b][1]=dy; tail[f-69][b][2]=dz; }
      }
      ax=bx; ay=by; az=bz;  bx=cx; by=cy; bz=cz;  cx=dx; cy=dy; cz=dz;
    }
  }
  __syncthreads();
  for(int kk=1; kk<24; ++kk){
    if(tid < 16){
      int b = tid;
      frame_cols(tail[0][b][0],tail[0][b][1],tail[0][b][2],
                 tail[1][b][0],tail[1][b][1],tail[1][b][2],
                 tail[2][b][0],tail[2][b][1],tail[2][b][2], &sR[b][0]);
      sorg[b][0]=tail[2][b][0]; sorg[b][1]=tail[2][b][1]; sorg[b][2]=tail[2][b][2];
    }
    __syncthreads();
    for(int idx=tid; idx<1152; idx+=blockDim.x){
      int f = idx >> 4, b = idx & 15;
      const float* v = frag + (((size_t)(f*24+kk))*16 + b)*3;
      float vx=v[0], vy=v[1], vz=v[2];
      float gx = sorg[b][0] + sR[b][0]*vx + sR[b][3]*vy + sR[b][6]*vz;
      float gy = sorg[b][1] + sR[b][1]*vx + sR[b][4]*vy + sR[b][7]*vz;
      float gz = sorg[b][2] + sR[b][2]*vx + sR[b][5]*vy + sR[b][8]*vz;
      float* o = out + (((size_t)(kk*72+f))*16 + b)*3;
      o[0]=gx; o[1]=gy; o[2]=gz;
      if(f >= 69){ tail[f-69][b][0]=gx; tail[f-69][b][1]=gy; tail[f-69][b][2]=gz; }
    }
    __syncthreads();
  }
}

// ---------------------------------------------------------------------------
extern "C" void kernel_launch(void* const* d_in, const int* in_sizes, int n_in,
                              void* d_out, int out_size, void* d_ws, size_t ws_size,
                              hipStream_t stream)
{
  (void)in_sizes; (void)n_in; (void)out_size; (void)ws_size;
  const int*   seq  = (const int*)d_in[0];
  const float* pssm = (const float*)d_in[1];
  const float* w_ih_l0f=(const float*)d_in[3];  const float* w_hh_l0f=(const float*)d_in[4];
  const float* b_ih_l0f=(const float*)d_in[5];  const float* b_hh_l0f=(const float*)d_in[6];
  const float* w_ih_l0b=(const float*)d_in[7];  const float* w_hh_l0b=(const float*)d_in[8];
  const float* b_ih_l0b=(const float*)d_in[9];  const float* b_hh_l0b=(const float*)d_in[10];
  const float* w_ih_l1f=(const float*)d_in[11]; const float* w_hh_l1f=(const float*)d_in[12];
  const float* b_ih_l1f=(const float*)d_in[13]; const float* b_hh_l1f=(const float*)d_in[14];
  const float* w_ih_l1b=(const float*)d_in[15]; const float* w_hh_l1b=(const float*)d_in[16];
  const float* b_ih_l1b=(const float*)d_in[17]; const float* b_hh_l1b=(const float*)d_in[18];
  const float* fc_w=(const float*)d_in[19];     const float* fc_b=(const float*)d_in[20];
  const float* alphabet=(const float*)d_in[21];
  const float* bl=(const float*)d_in[22];       const float* ba=(const float*)d_in[23];
  float* out = (float*)d_out;

  char* ws = (char*)d_ws;
  size_t o = 0;
  auto alloc = [&](size_t bytes){ size_t r = o; o = (o + bytes + 255) & ~(size_t)255; return r; };
  size_t o_wphh = alloc(4ull*320000*16);   // 20.48 MB  W_hh frags (4 dirs)
  size_t o_wp1  = alloc(2ull*640000*16);   // 20.48 MB  W_ih_l1 frags
  size_t o_wp0  = alloc(2ull*25600*16);    //  0.82 MB  W_ih_l0 frags (padded K=64)
  size_t o_gpf  = alloc(2ull*29491200);    // 58.98 MB  Gp fwd (reused layer0->layer1)
  size_t o_gpb  = alloc(2ull*29491200);    // 58.98 MB  Gp bwd
  size_t o_h0   = alloc(2ull*14745600);    // 29.49 MB  h0 f16 (L,16,1600)
  size_t o_h1   = alloc(2ull*14745600);    // 29.49 MB  h1 f16
  size_t o_x    = alloc(2ull*589824);      //  1.18 MB  x f16 (9216,64)
  size_t o_z    = alloc(2ull*25600);       //  zero hidden
  size_t o_srf  = alloc(4ull*82944);       //  SRF
  size_t o_frag = alloc(4ull*82944);       //  pnerf fragments
  size_t o_bar  = alloc(256);              //  barrier (total ~220 MB)

  h8* wp_hh = (h8*)(ws + o_wphh);
  h8* wp1   = (h8*)(ws + o_wp1);
  h8* wp0   = (h8*)(ws + o_wp0);
  _Float16* gpf = (_Float16*)(ws + o_gpf);
  _Float16* gpb = (_Float16*)(ws + o_gpb);
  _Float16* h0  = (_Float16*)(ws + o_h0);
  _Float16* h1  = (_Float16*)(ws + o_h1);
  _Float16* x   = (_Float16*)(ws + o_x);
  _Float16* zb  = (_Float16*)(ws + o_z);
  float* srf    = (float*)(ws + o_srf);
  float* frag   = (float*)(ws + o_frag);
  int* bar      = (int*)(ws + o_bar);

  init_kernel<<<100, 256, 0, stream>>>(zb, bar);
  build_x<<<2304, 256, 0, stream>>>(seq, pssm, x);
  prep_w<<<10200, 256, 0, stream>>>(w_hh_l0f, w_hh_l0b, w_hh_l1f, w_hh_l1b,
                                    w_ih_l1f, w_ih_l1b, w_ih_l0f, w_ih_l0b,
                                    wp_hh, wp1, wp0);
  // layer 0 input projection (K padded to 64)
  gemm_gp<<<14400, 256, 0, stream>>>(x, 64, KQ_L0, wp0, wp0 + 25600,
                                     b_ih_l0f, b_hh_l0f, b_ih_l0b, b_hh_l0b, gpf, gpb);
  // layer 0 recurrence
  lstm_kernel<<<100, 256, 0, stream>>>(wp_hh, wp_hh + 320000, gpf, gpb, h0, zb, bar, 0);
  // layer 1 input projection (K=1600 over h0)
  gemm_gp<<<14400, 256, 0, stream>>>(h0, 1600, KQ_L1, wp1, wp1 + 640000,
                                     b_ih_l1f, b_hh_l1f, b_ih_l1b, b_hh_l1b, gpf, gpb);
  // layer 1 recurrence (barrier generation continues at 575)
  lstm_kernel<<<100, 256, 0, stream>>>(wp_hh + 640000, wp_hh + 960000, gpf, gpb, h1, zb, bar, 575);
  // fc head -> torsions -> SRF
  head_kernel<<<576, 256, 0, stream>>>(h1, fc_w, fc_b, alphabet, bl, ba, srf);
  // geometric chain
  pnerf_kernel<<<1, 512, 0, stream>>>(srf, frag, out);
}

// Round 2
// 6619.234 us; speedup vs baseline: 2.8152x; 2.8152x over previous
//
#include <hip/hip_runtime.h>
#include <hip/hip_fp16.h>

// Problem constants
#define L_SEQ 576
#define BATCH 16
#define HIDDEN 800
#define NT 200      // N tiles per direction (3200/16)
#define KQ_HH 25    // K chunks for W_hh (800/32)
#define KQ_L1 50    // 1600/32
#define KQ_L0 2     // padded 64/32
#define LBLK 25     // lstm blocks per direction

typedef _Float16 h8 __attribute__((ext_vector_type(8)));
typedef _Float16 h4 __attribute__((ext_vector_type(4)));
typedef float f4 __attribute__((ext_vector_type(4)));
typedef int v4i __attribute__((ext_vector_type(4)));
typedef int v2i __attribute__((ext_vector_type(2)));

__device__ __forceinline__ float sigmoidf_(float x){
  x = fminf(30.f, fmaxf(-30.f, x));
  return 1.f/(1.f+__expf(-x));
}
__device__ __forceinline__ float tanhf_(float x){
  x = fminf(15.f, fmaxf(-15.f, x));
  float e = __expf(2.f*x);
  return (e-1.f)/(e+1.f);
}

// ---------------- init: zero the per-step arrival flags ---------------------
__global__ void init_kernel(int* flags){
  int i = blockIdx.x*256 + threadIdx.x;
  if(i < 4*L_SEQ) flags[i] = 0;
}

// ---------------- build x (L*B, 64) f16: [onehot(20) | pssm(21) | pad0] -----
__global__ void build_x(const int* __restrict__ seq, const float* __restrict__ pssm,
                        _Float16* __restrict__ x){
  int i = blockIdx.x*256 + threadIdx.x;
  if(i >= L_SEQ*BATCH*64) return;
  int m = i >> 6, k = i & 63;
  float v = 0.f;
  if(k < 20)      v = (seq[m]==k) ? 1.f : 0.f;
  else if(k < 41) v = pssm[m*21 + (k-20)];
  x[i] = (_Float16)v;
}

// ---------------- weight prep: fp32 -> f16 MFMA B-fragment layout ------------
// B-frag: lane l holds B[k=q*32+(l>>4)*8+j][n = tile*16 + (l&15)], j=0..7
// n-permutation: col c=l&15 -> unit u = T*4 + (c>>2), gate g = c&3, W row = g*800+u
__global__ void prep_w(
  const float* __restrict__ whh0f, const float* __restrict__ whh0b,
  const float* __restrict__ whh1f, const float* __restrict__ whh1b,
  const float* __restrict__ wih1f, const float* __restrict__ wih1b,
  const float* __restrict__ wih0f, const float* __restrict__ wih0b,
  h8* __restrict__ wp_hh, h8* __restrict__ wp1, h8* __restrict__ wp0)
{
  long idx = (long)blockIdx.x*256 + threadIdx.x;
  const long J1 = 4L*320000, J2 = 2L*640000, J3 = 2L*25600;
  if(idx < J1){
    int d = (int)(idx/320000); int r = (int)(idx%320000);
    int T = r/1600, q = (r%1600)/64, l = r&63;
    const float* W = (d==0)?whh0f:(d==1)?whh0b:(d==2)?whh1f:whh1b;
    int c = l&15; int n = (c&3)*800 + T*4 + (c>>2);
    const float* src = W + (size_t)n*800 + q*32 + ((l>>4)<<3);
    h8 v;
    #pragma unroll
    for(int j=0;j<8;++j) v[j] = (_Float16)src[j];
    wp_hh[idx] = v;
  } else if(idx < J1+J2){
    long i2 = idx - J1;
    int d = (int)(i2/640000); int r = (int)(i2%640000);
    int T = r/3200, q = (r%3200)/64, l = r&63;
    const float* W = d ? wih1b : wih1f;
    int c = l&15; int n = (c&3)*800 + T*4 + (c>>2);
    const float* src = W + (size_t)n*1600 + q*32 + ((l>>4)<<3);
    h8 v;
    #pragma unroll
    for(int j=0;j<8;++j) v[j] = (_Float16)src[j];
    wp1[i2] = v;
  } else if(idx < J1+J2+J3){
    long i3 = idx - J1 - J2;
    int d = (int)(i3/25600); int r = (int)(i3%25600);
    int T = r/128, q = (r%128)/64, l = r&63;
    const float* W = d ? wih0b : wih0f;
    int c = l&15; int n = (c&3)*800 + T*4 + (c>>2);
    int k0 = q*32 + ((l>>4)<<3);
    h8 v;
    #pragma unroll
    for(int j=0;j<8;++j){ int k = k0+j; v[j] = (_Float16)((k<41)? W[(size_t)n*41+k] : 0.f); }
    wp0[i3] = v;
  }
}

// ------------- input-projection GEMM -> permuted Gp layout (f16) -------------
// Gp[((t*200+T)*64+l)*4 + r] = G[t][b=(l>>4)*4+r][n(T, c=l&15)]   (bias included)
__global__ __launch_bounds__(256) void gemm_gp(
  const _Float16* __restrict__ A, int lda, int KQ,
  const h8* __restrict__ WpF, const h8* __restrict__ WpB,
  const float* __restrict__ bihF, const float* __restrict__ bhhF,
  const float* __restrict__ bihB, const float* __restrict__ bhhB,
  _Float16* __restrict__ GpF, _Float16* __restrict__ GpB)
{
  const int wv = threadIdx.x >> 6;
  const int l  = threadIdx.x & 63;
  const int mg = blockIdx.x % 144;
  const int tg = blockIdx.x / 144;       // 0..99
  const int mt = mg*4 + wv;              // 0..575  (one timestep = 16 rows)
  const int dir = tg / 50;
  const int Tb  = (tg % 50) * 4;
  const h8* Wp = dir ? WpB : WpF;
  const float* bih = dir ? bihB : bihF;
  const float* bhh = dir ? bhhB : bhhF;
  _Float16* Gp = dir ? GpB : GpF;

  const _Float16* ab = A + (size_t)(mt*16 + (l&15))*lda + ((l>>4)<<3);
  f4 acc[4] = {{0.f,0.f,0.f,0.f},{0.f,0.f,0.f,0.f},{0.f,0.f,0.f,0.f},{0.f,0.f,0.f,0.f}};
  for(int q=0;q<KQ;++q){
    h8 av = *(const h8*)(ab + q*32);
    #pragma unroll
    for(int j=0;j<4;++j){
      h8 bv = Wp[((size_t)(Tb+j)*KQ + q)*64 + l];
      acc[j] = __builtin_amdgcn_mfma_f32_16x16x32_f16(av, bv, acc[j], 0, 0, 0);
    }
  }
  const int c = l & 15;
  #pragma unroll
  for(int j=0;j<4;++j){
    int T = Tb + j;
    int n = (c&3)*800 + T*4 + (c>>2);
    float bias = bih[n] + bhh[n];
    h4 o;
    o[0]=(_Float16)(acc[j][0]+bias); o[1]=(_Float16)(acc[j][1]+bias);
    o[2]=(_Float16)(acc[j][2]+bias); o[3]=(_Float16)(acc[j][3]+bias);
    *(h4*)(Gp + (((size_t)mt*NT + T)*64 + l)*4) = o;
  }
}

// ---------------- persistent LSTM layer (fence-free LLC sync) ----------------
// 50 blocks x 512 threads. Blocks 0..24 forward, 25..49 backward. Each wave
// owns one 16-col gate tile; W_hh fragments pinned in VGPRs. Cross-XCD h/flag
// traffic goes through device-scope (sc1) loads/stores -> Infinity Cache; no
// cache-wide fences. Per-step per-direction arrival counters, arity 25.
__global__ __launch_bounds__(512,2) void lstm_kernel(
  const h8* __restrict__ WpF, const h8* __restrict__ WpB,
  const _Float16* __restrict__ GpF, const _Float16* __restrict__ GpB,
  _Float16* __restrict__ h, int* __restrict__ flags)
{
  __shared__ h8 sh[1600];   // h_prev tile in MFMA A-fragment order (25.6 KB)
  const int tid = threadIdx.x;
  const int wv  = tid >> 6;
  const int l   = tid & 63;
  const bool bwd = blockIdx.x >= LBLK;
  const int T = ((bwd ? (int)blockIdx.x - LBLK : (int)blockIdx.x) << 3) + wv; // 0..199
  const h8* Wp = bwd ? WpB : WpF;
  const _Float16* Gp = bwd ? GpB : GpF;
  const int col_off = bwd ? HIDDEN : 0;
  int* flg = flags + (bwd ? L_SEQ : 0);

  h8 Bf[KQ_HH];
  #pragma unroll
  for(int q=0;q<KQ_HH;++q) Bf[q] = Wp[(T*KQ_HH + q)*64 + l];
  #pragma unroll
  for(int q=0;q<KQ_HH;++q) asm volatile("" : "+v"(Bf[q]));   // pin: no remat

  float cs[4] = {0.f,0.f,0.f,0.f};
  const int m  = l & 15;
  const int lb = l & ~3;

  for(int s=0; s<L_SEQ; ++s){
    const int t = bwd ? (L_SEQ-1-s) : s;

    if(s > 0){
      if(tid == 0){
        const unsigned long long fa = (unsigned long long)(flg + (s-1));
        int v;
        for(;;){
          asm volatile("global_load_dword %0, %1, off sc1\n\ts_waitcnt vmcnt(0)"
                       : "=v"(v) : "v"(fa) : "memory");
          if(v >= LBLK) break;
          __builtin_amdgcn_s_sleep(1);
        }
      }
      __syncthreads();
      // stage h[t_prev] (this direction's half) into LDS in fragment order
      const _Float16* src = h + (size_t)(bwd ? t+1 : t-1)*(BATCH*1600) + col_off;
      const int c0 = tid, c1 = tid+512, c2 = tid+1024, c3 = tid+1536;
      v4i w0={0,0,0,0}, w1={0,0,0,0}, w2={0,0,0,0}, w3={0,0,0,0};
      #define STAGE_ADDR(c) ((unsigned long long)(src + (size_t)(((c)&15)*1600 + ((c)>>6)*32 + ((((c)&63)>>4))*8)))
      asm volatile("global_load_dwordx4 %0, %1, off sc1" : "=v"(w0) : "v"(STAGE_ADDR(c0)) : "memory");
      asm volatile("global_load_dwordx4 %0, %1, off sc1" : "=v"(w1) : "v"(STAGE_ADDR(c1)) : "memory");
      asm volatile("global_load_dwordx4 %0, %1, off sc1" : "=v"(w2) : "v"(STAGE_ADDR(c2)) : "memory");
      if(tid < 64)
        asm volatile("global_load_dwordx4 %0, %1, off sc1" : "=v"(w3) : "v"(STAGE_ADDR(c3)) : "memory");
      #undef STAGE_ADDR
      asm volatile("s_waitcnt vmcnt(0)" : "+v"(w0),"+v"(w1),"+v"(w2),"+v"(w3) : : "memory");
      sh[c0] = __builtin_bit_cast(h8, w0);
      sh[c1] = __builtin_bit_cast(h8, w1);
      sh[c2] = __builtin_bit_cast(h8, w2);
      if(tid < 64) sh[c3] = __builtin_bit_cast(h8, w3);
      __syncthreads();
    }

    // gates = Gp[t] + h_prev @ W_hh^T
    h4 gp4 = *(const h4*)(Gp + (((size_t)t*NT + T)*64 + l)*4);
    f4 acc0, acc1;
    acc0[0]=(float)gp4[0]; acc0[1]=(float)gp4[1]; acc0[2]=(float)gp4[2]; acc0[3]=(float)gp4[3];
    acc1[0]=0.f; acc1[1]=0.f; acc1[2]=0.f; acc1[3]=0.f;
    if(s > 0){
      #pragma unroll
      for(int q=0;q<KQ_HH;++q){
        h8 av = sh[q*64 + l];
        if(q & 1) acc1 = __builtin_amdgcn_mfma_f32_16x16x32_f16(av, Bf[q], acc1, 0,0,0);
        else      acc0 = __builtin_amdgcn_mfma_f32_16x16x32_f16(av, Bf[q], acc0, 0,0,0);
      }
    }
    f4 g = acc0 + acc1;

    float hv[4];
    #pragma unroll
    for(int r=0;r<4;++r){
      float iv = __shfl(g[r], lb+0, 64);
      float fv = __shfl(g[r], lb+1, 64);
      float gv = __shfl(g[r], lb+2, 64);
      float ov = __shfl(g[r], lb+3, 64);
      float cn = sigmoidf_(fv)*cs[r] + sigmoidf_(iv)*tanhf_(gv);
      cs[r] = cn;
      hv[r] = sigmoidf_(ov)*tanhf_(cn);
    }

    // pack to 8B rows and store via sc1 (write-through to LLC).
    // lane i<16 stores batch row (i&3)*4+r in round r==i>>2, cols T*4..T*4+3.
    _Float16* hrow = h + (size_t)t*(BATCH*1600) + col_off + T*4;
    #pragma unroll
    for(int r=0;r<4;++r){
      const int srcl = (l&3) << 4;
      float v0 = __shfl(hv[r], srcl+0, 64);
      float v1 = __shfl(hv[r], srcl+4, 64);
      float v2 = __shfl(hv[r], srcl+8, 64);
      float v3 = __shfl(hv[r], srcl+12, 64);
      if((l >> 2) == r){
        h4 o; o[0]=(_Float16)v0; o[1]=(_Float16)v1; o[2]=(_Float16)v2; o[3]=(_Float16)v3;
        unsigned long long ad = (unsigned long long)(hrow + (size_t)((l&3)*4 + r)*1600);
        v2i ov = __builtin_bit_cast(v2i, o);
        asm volatile("global_store_dwordx2 %0, %1, off sc1" : : "v"(ad), "v"(ov) : "memory");
      }
    }
    asm volatile("s_waitcnt vmcnt(0)" : : : "memory");   // stores acked at LLC
    __syncthreads();                                      // whole block done
    if(tid == 0 && s != L_SEQ-1) atomicAdd(flg + s, 1);  // device-scope arrive
  }
}

// ---------------- head: fc -> softmax-free atan2 -> SRF ---------------------
__global__ void head_kernel(const _Float16* __restrict__ h1,
                            const float* __restrict__ fcw, const float* __restrict__ fcb,
                            const float* __restrict__ alphabet,
                            const float* __restrict__ bl, const float* __restrict__ ba,
                            float* __restrict__ srf)
{
  __shared__ _Float16 sh[16*1608];   // padded stride: 804 words % 32 = 4 -> conflict-free
  __shared__ float slog[960];
  __shared__ float smax[16];
  __shared__ float sphi[48];
  const int t = blockIdx.x, tid = threadIdx.x;
  const h4* src4 = (const h4*)(h1 + (size_t)t*25600);
  h4* dst4 = (h4*)sh;
  for(int i=tid; i<6400; i+=256){
    int m = i/400, k = i%400;
    dst4[m*402 + k] = src4[i];
  }
  __syncthreads();
  for(int it=tid; it<960; it+=256){
    int j = it >> 4, b = it & 15;
    float acc = fcb[j];
    const float4* wr = (const float4*)(fcw + (size_t)j*1600);
    const h4* hr = (const h4*)(sh + b*1608);
    for(int k=0;k<400;++k){
      float4 wv = wr[k]; h4 hv = hr[k];
      acc += wv.x*(float)hv[0] + wv.y*(float)hv[1] + wv.z*(float)hv[2] + wv.w*(float)hv[3];
    }
    slog[b*60 + j] = acc;
  }
  __syncthreads();
  if(tid < 16){
    float mx = -1e30f;
    for(int j=0;j<60;++j) mx = fmaxf(mx, slog[tid*60+j]);
    smax[tid] = mx;
  }
  __syncthreads();
  if(tid < 48){
    int b = tid/3, ax = tid%3;
    float s=0.f, c=0.f, mx = smax[b];
    for(int j=0;j<60;++j){
      float e = __expf(slog[b*60+j] - mx);
      float al = alphabet[j*3 + ax];
      s += e*__sinf(al); c += e*__cosf(al);
    }
    sphi[b*3+ax] = atan2f(s, c);   // softmax denominator cancels in atan2
  }
  __syncthreads();
  if(tid < 144){
    int jj = tid/48; int r_ = tid%48; int b = r_/3, ax = r_%3;
    float rr = bl[jj], th = ba[jj], ph = sphi[b*3+jj];
    float v = (ax==0) ? rr*__cosf(th)
            : (ax==1) ? rr*__cosf(ph)*__sinf(th)
                      : rr*__sinf(ph)*__sinf(th);
    srf[(((size_t)(3*t+jj))*16 + b)*3 + ax] = v;
  }
}

// ---------------- pNeRF: 384 chain scans + 23 fragment stitches -------------
__device__ __forceinline__ void frame_cols(
  float ax,float ay,float az, float bx,float by,float bz, float cx,float cy,float cz,
  float* R)
{
  float ux=cx-bx, uy=cy-by, uz=cz-bz;
  float ir = rsqrtf(ux*ux+uy*uy+uz*uz);
  float bcx=ux*ir, bcy=uy*ir, bcz=uz*ir;
  float px=bx-ax, py=by-ay, pz=bz-az;
  float nx=py*bcz-pz*bcy, ny=pz*bcx-px*bcz, nz=px*bcy-py*bcx;
  float in_ = rsqrtf(nx*nx+ny*ny+nz*nz);
  nx*=in_; ny*=in_; nz*=in_;
  float mx=ny*bcz-nz*bcy, my=nz*bcx-nx*bcz, mz=nx*bcy-ny*bcx;
  R[0]=bcx;R[1]=bcy;R[2]=bcz; R[3]=mx;R[4]=my;R[5]=mz; R[6]=nx;R[7]=ny;R[8]=nz;
}

__global__ void pnerf_kernel(const float* __restrict__ srf,
                             float* __restrict__ frag, float* __restrict__ out)
{
  __shared__ float tail[3][16][3];
  __shared__ float sR[16][9];
  __shared__ float sorg[16][3];
  const int tid = threadIdx.x;
  if(tid < 384){
    int k = tid >> 4, b = tid & 15;
    float ax=-0.70710678f, ay=1.22474487f, az=0.f;
    float bx=-1.41421356f, by=0.f, bz=0.f;
    float cx=0.f, cy=0.f, cz=0.f;
    for(int f=0; f<72; ++f){
      const float* ct = srf + (((size_t)(k*72+f))*16 + b)*3;
      float t0=ct[0], t1=ct[1], t2=ct[2];
      float R[9];
      frame_cols(ax,ay,az, bx,by,bz, cx,cy,cz, R);
      float dx = cx + R[0]*t0 + R[3]*t1 + R[6]*t2;
      float dy = cy + R[1]*t0 + R[4]*t1 + R[7]*t2;
      float dz = cz + R[2]*t0 + R[5]*t1 + R[8]*t2;
      float* fr = frag + (((size_t)(f*24+k))*16 + b)*3;
      fr[0]=dx; fr[1]=dy; fr[2]=dz;
      if(k == 0){
        float* o = out + ((size_t)(f*16)+b)*3;
        o[0]=dx; o[1]=dy; o[2]=dz;
        if(f >= 69){ tail[f-69][b][0]=dx; tail[f-69][b][1]=dy; tail[f-69][b][2]=dz; }
      }
      ax=bx; ay=by; az=bz;  bx=cx; by=cy; bz=cz;  cx=dx; cy=dy; cz=dz;
    }
  }
  __syncthreads();
  for(int kk=1; kk<24; ++kk){
    if(tid < 16){
      int b = tid;
      frame_cols(tail[0][b][0],tail[0][b][1],tail[0][b][2],
                 tail[1][b][0],tail[1][b][1],tail[1][b][2],
                 tail[2][b][0],tail[2][b][1],tail[2][b][2], &sR[b][0]);
      sorg[b][0]=tail[2][b][0]; sorg[b][1]=tail[2][b][1]; sorg[b][2]=tail[2][b][2];
    }
    __syncthreads();
    for(int idx=tid; idx<1152; idx+=blockDim.x){
      int f = idx >> 4, b = idx & 15;
      const float* v = frag + (((size_t)(f*24+kk))*16 + b)*3;
      float vx=v[0], vy=v[1], vz=v[2];
      float gx = sorg[b][0] + sR[b][0]*vx + sR[b][3]*vy + sR[b][6]*vz;
      float gy = sorg[b][1] + sR[b][1]*vx + sR[b][4]*vy + sR[b][7]*vz;
      float gz = sorg[b][2] + sR[b][2]*vx + sR[b][5]*vy + sR[b][8]*vz;
      float* o = out + (((size_t)(kk*72+f))*16 + b)*3;
      o[0]=gx; o[1]=gy; o[2]=gz;
      if(f >= 69){ tail[f-69][b][0]=gx; tail[f-69][b][1]=gy; tail[f-69][b][2]=gz; }
    }
    __syncthreads();
  }
}

// ---------------------------------------------------------------------------
extern "C" void kernel_launch(void* const* d_in, const int* in_sizes, int n_in,
                              void* d_out, int out_size, void* d_ws, size_t ws_size,
                              hipStream_t stream)
{
  (void)in_sizes; (void)n_in; (void)out_size; (void)ws_size;
  const int*   seq  = (const int*)d_in[0];
  const float* pssm = (const float*)d_in[1];
  const float* w_ih_l0f=(const float*)d_in[3];  const float* w_hh_l0f=(const float*)d_in[4];
  const float* b_ih_l0f=(const float*)d_in[5];  const float* b_hh_l0f=(const float*)d_in[6];
  const float* w_ih_l0b=(const float*)d_in[7];  const float* w_hh_l0b=(const float*)d_in[8];
  const float* b_ih_l0b=(const float*)d_in[9];  const float* b_hh_l0b=(const float*)d_in[10];
  const float* w_ih_l1f=(const float*)d_in[11]; const float* w_hh_l1f=(const float*)d_in[12];
  const float* b_ih_l1f=(const float*)d_in[13]; const float* b_hh_l1f=(const float*)d_in[14];
  const float* w_ih_l1b=(const float*)d_in[15]; const float* w_hh_l1b=(const float*)d_in[16];
  const float* b_ih_l1b=(const float*)d_in[17]; const float* b_hh_l1b=(const float*)d_in[18];
  const float* fc_w=(const float*)d_in[19];     const float* fc_b=(const float*)d_in[20];
  const float* alphabet=(const float*)d_in[21];
  const float* bl=(const float*)d_in[22];       const float* ba=(const float*)d_in[23];
  float* out = (float*)d_out;

  char* ws = (char*)d_ws;
  size_t o = 0;
  auto alloc = [&](size_t bytes){ size_t r = o; o = (o + bytes + 255) & ~(size_t)255; return r; };
  size_t o_wphh = alloc(4ull*320000*16);   // 20.48 MB  W_hh frags (4 dirs)
  size_t o_wp1  = alloc(2ull*640000*16);   // 20.48 MB  W_ih_l1 frags
  size_t o_wp0  = alloc(2ull*25600*16);    //  0.82 MB  W_ih_l0 frags (padded K=64)
  size_t o_gpf  = alloc(2ull*29491200);    // 58.98 MB  Gp fwd (reused layer0->layer1)
  size_t o_gpb  = alloc(2ull*29491200);    // 58.98 MB  Gp bwd
  size_t o_h0   = alloc(2ull*14745600);    // 29.49 MB  h0 f16 (L,16,1600)
  size_t o_h1   = alloc(2ull*14745600);    // 29.49 MB  h1 f16
  size_t o_x    = alloc(2ull*589824);      //  1.18 MB  x f16 (9216,64)
  size_t o_srf  = alloc(4ull*82944);       //  SRF
  size_t o_frag = alloc(4ull*82944);       //  pnerf fragments
  size_t o_flag = alloc(4ull*4*L_SEQ);     //  per-step arrival flags (2 layers x 2 dirs)

  h8* wp_hh = (h8*)(ws + o_wphh);
  h8* wp1   = (h8*)(ws + o_wp1);
  h8* wp0   = (h8*)(ws + o_wp0);
  _Float16* gpf = (_Float16*)(ws + o_gpf);
  _Float16* gpb = (_Float16*)(ws + o_gpb);
  _Float16* h0  = (_Float16*)(ws + o_h0);
  _Float16* h1  = (_Float16*)(ws + o_h1);
  _Float16* x   = (_Float16*)(ws + o_x);
  float* srf    = (float*)(ws + o_srf);
  float* frag   = (float*)(ws + o_frag);
  int* flags    = (int*)(ws + o_flag);

  init_kernel<<<9, 256, 0, stream>>>(flags);
  build_x<<<2304, 256, 0, stream>>>(seq, pssm, x);
  prep_w<<<10200, 256, 0, stream>>>(w_hh_l0f, w_hh_l0b, w_hh_l1f, w_hh_l1b,
                                    w_ih_l1f, w_ih_l1b, w_ih_l0f, w_ih_l0b,
                                    wp_hh, wp1, wp0);
  // layer 0 input projection (K padded to 64)
  gemm_gp<<<14400, 256, 0, stream>>>(x, 64, KQ_L0, wp0, wp0 + 25600,
                                     b_ih_l0f, b_hh_l0f, b_ih_l0b, b_hh_l0b, gpf, gpb);
  // layer 0 recurrence
  lstm_kernel<<<50, 512, 0, stream>>>(wp_hh, wp_hh + 320000, gpf, gpb, h0, flags);
  // layer 1 input projection (K=1600 over h0)
  gemm_gp<<<14400, 256, 0, stream>>>(h0, 1600, KQ_L1, wp1, wp1 + 640000,
                                     b_ih_l1f, b_hh_l1f, b_ih_l1b, b_hh_l1b, gpf, gpb);
  // layer 1 recurrence (separate flag block)
  lstm_kernel<<<50, 512, 0, stream>>>(wp_hh + 640000, wp_hh + 960000, gpf, gpb, h1,
                                      flags + 2*L_SEQ);
  // fc head -> torsions -> SRF
  head_kernel<<<576, 256, 0, stream>>>(h1, fc_w, fc_b, alphabet, bl, ba, srf);
  // geometric chain
  pnerf_kernel<<<1, 512, 0, stream>>>(srf, frag, out);
}

// Round 3
// 6493.027 us; speedup vs baseline: 2.8699x; 1.0194x over previous
//
#include <hip/hip_runtime.h>
#include <hip/hip_fp16.h>

// Problem constants
#define L_SEQ 576
#define BATCH 16
#define HIDDEN 800
#define NT 200      // N tiles per direction (3200/16)
#define KQ_HH 25    // K chunks for W_hh (800/32)
#define KQ_L1 50    // 1600/32
#define KQ_L0 2     // padded 64/32
#define LBLK 50     // lstm blocks per direction (4 waves x 4 tiles each... 1 tile/wave)

typedef _Float16 h8 __attribute__((ext_vector_type(8)));
typedef _Float16 h4 __attribute__((ext_vector_type(4)));
typedef float f4 __attribute__((ext_vector_type(4)));
typedef int v4i __attribute__((ext_vector_type(4)));
typedef int v2i __attribute__((ext_vector_type(2)));

__device__ __forceinline__ float sigmoidf_(float x){
  x = fminf(30.f, fmaxf(-30.f, x));
  return 1.f/(1.f+__expf(-x));
}
__device__ __forceinline__ float tanhf_(float x){
  x = fminf(15.f, fmaxf(-15.f, x));
  float e = __expf(2.f*x);
  return (e-1.f)/(e+1.f);
}

// ---------------- init: zero the per-(layer,dir) flag regions ---------------
__global__ void init_kernel(int* flags){
  flags[threadIdx.x] = 0;   // 256 words = 4 regions x 64
}

// ---------------- build x (L*B, 64) f16: [onehot(20) | pssm(21) | pad0] -----
__global__ void build_x(const int* __restrict__ seq, const float* __restrict__ pssm,
                        _Float16* __restrict__ x){
  int i = blockIdx.x*256 + threadIdx.x;
  if(i >= L_SEQ*BATCH*64) return;
  int m = i >> 6, k = i & 63;
  float v = 0.f;
  if(k < 20)      v = (seq[m]==k) ? 1.f : 0.f;
  else if(k < 41) v = pssm[m*21 + (k-20)];
  x[i] = (_Float16)v;
}

// ---------------- weight prep: fp32 -> f16 MFMA B-fragment layout ------------
// B-frag: lane l holds B[k=q*32+(l>>4)*8+j][n = tile*16 + (l&15)], j=0..7
// n-permutation: col c=l&15 -> unit u = T*4 + (c>>2), gate g = c&3, W row = g*800+u
__global__ void prep_w(
  const float* __restrict__ whh0f, const float* __restrict__ whh0b,
  const float* __restrict__ whh1f, const float* __restrict__ whh1b,
  const float* __restrict__ wih1f, const float* __restrict__ wih1b,
  const float* __restrict__ wih0f, const float* __restrict__ wih0b,
  h8* __restrict__ wp_hh, h8* __restrict__ wp1, h8* __restrict__ wp0)
{
  long idx = (long)blockIdx.x*256 + threadIdx.x;
  const long J1 = 4L*320000, J2 = 2L*640000, J3 = 2L*25600;
  if(idx < J1){
    int d = (int)(idx/320000); int r = (int)(idx%320000);
    int T = r/1600, q = (r%1600)/64, l = r&63;
    const float* W = (d==0)?whh0f:(d==1)?whh0b:(d==2)?whh1f:whh1b;
    int c = l&15; int n = (c&3)*800 + T*4 + (c>>2);
    const float* src = W + (size_t)n*800 + q*32 + ((l>>4)<<3);
    h8 v;
    #pragma unroll
    for(int j=0;j<8;++j) v[j] = (_Float16)src[j];
    wp_hh[idx] = v;
  } else if(idx < J1+J2){
    long i2 = idx - J1;
    int d = (int)(i2/640000); int r = (int)(i2%640000);
    int T = r/3200, q = (r%3200)/64, l = r&63;
    const float* W = d ? wih1b : wih1f;
    int c = l&15; int n = (c&3)*800 + T*4 + (c>>2);
    const float* src = W + (size_t)n*1600 + q*32 + ((l>>4)<<3);
    h8 v;
    #pragma unroll
    for(int j=0;j<8;++j) v[j] = (_Float16)src[j];
    wp1[i2] = v;
  } else if(idx < J1+J2+J3){
    long i3 = idx - J1 - J2;
    int d = (int)(i3/25600); int r = (int)(i3%25600);
    int T = r/128, q = (r%128)/64, l = r&63;
    const float* W = d ? wih0b : wih0f;
    int c = l&15; int n = (c&3)*800 + T*4 + (c>>2);
    int k0 = q*32 + ((l>>4)<<3);
    h8 v;
    #pragma unroll
    for(int j=0;j<8;++j){ int k = k0+j; v[j] = (_Float16)((k<41)? W[(size_t)n*41+k] : 0.f); }
    wp0[i3] = v;
  }
}

// ------------- layer-0 input projection (x row-major, lda=64) ---------------
// Gp[((t*200+T)*64+l)*4 + r] = G[t][b=(l>>4)*4+r][n(T, c=l&15)]   (bias included)
__global__ __launch_bounds__(256) void gemm_l0(
  const _Float16* __restrict__ A,
  const h8* __restrict__ WpF, const h8* __restrict__ WpB,
  const float* __restrict__ bihF, const float* __restrict__ bhhF,
  const float* __restrict__ bihB, const float* __restrict__ bhhB,
  _Float16* __restrict__ GpF, _Float16* __restrict__ GpB)
{
  const int wv = threadIdx.x >> 6;
  const int l  = threadIdx.x & 63;
  const int mg = blockIdx.x % 144;
  const int tg = blockIdx.x / 144;       // 0..99
  const int mt = mg*4 + wv;              // 0..575
  const int dir = tg / 50;
  const int Tb  = (tg % 50) * 4;
  const h8* Wp = dir ? WpB : WpF;
  const float* bih = dir ? bihB : bihF;
  const float* bhh = dir ? bhhB : bhhF;
  _Float16* Gp = dir ? GpB : GpF;

  const _Float16* ab = A + (size_t)(mt*16 + (l&15))*64 + ((l>>4)<<3);
  f4 acc[4] = {{0.f,0.f,0.f,0.f},{0.f,0.f,0.f,0.f},{0.f,0.f,0.f,0.f},{0.f,0.f,0.f,0.f}};
  for(int q=0;q<KQ_L0;++q){
    h8 av = *(const h8*)(ab + q*32);
    #pragma unroll
    for(int j=0;j<4;++j){
      h8 bv = Wp[((size_t)(Tb+j)*KQ_L0 + q)*64 + l];
      acc[j] = __builtin_amdgcn_mfma_f32_16x16x32_f16(av, bv, acc[j], 0, 0, 0);
    }
  }
  const int c = l & 15;
  #pragma unroll
  for(int j=0;j<4;++j){
    int T = Tb + j;
    int n = (c&3)*800 + T*4 + (c>>2);
    float bias = bih[n] + bhh[n];
    h4 o;
    o[0]=(_Float16)(acc[j][0]+bias); o[1]=(_Float16)(acc[j][1]+bias);
    o[2]=(_Float16)(acc[j][2]+bias); o[3]=(_Float16)(acc[j][3]+bias);
    *(h4*)(Gp + (((size_t)mt*NT + T)*64 + l)*4) = o;
  }
}

// ------------- layer-1 input projection (h0 in fragment layout) --------------
// h0frag[t*3200 + q*64 + l] IS the A-fragment for (row m=l&15, k=q*32+(l>>4)*8..)
__global__ __launch_bounds__(256) void gemm_l1(
  const h8* __restrict__ Af,
  const h8* __restrict__ WpF, const h8* __restrict__ WpB,
  const float* __restrict__ bihF, const float* __restrict__ bhhF,
  const float* __restrict__ bihB, const float* __restrict__ bhhB,
  _Float16* __restrict__ GpF, _Float16* __restrict__ GpB)
{
  const int wv = threadIdx.x >> 6;
  const int l  = threadIdx.x & 63;
  const int mg = blockIdx.x % 144;
  const int tg = blockIdx.x / 144;
  const int mt = mg*4 + wv;
  const int dir = tg / 50;
  const int Tb  = (tg % 50) * 4;
  const h8* Wp = dir ? WpB : WpF;
  const float* bih = dir ? bihB : bihF;
  const float* bhh = dir ? bhhB : bhhF;
  _Float16* Gp = dir ? GpB : GpF;

  const h8* arow = Af + (size_t)mt*3200 + l;
  f4 acc[4] = {{0.f,0.f,0.f,0.f},{0.f,0.f,0.f,0.f},{0.f,0.f,0.f,0.f},{0.f,0.f,0.f,0.f}};
  for(int q=0;q<KQ_L1;++q){
    h8 av = arow[q*64];
    #pragma unroll
    for(int j=0;j<4;++j){
      h8 bv = Wp[((size_t)(Tb+j)*KQ_L1 + q)*64 + l];
      acc[j] = __builtin_amdgcn_mfma_f32_16x16x32_f16(av, bv, acc[j], 0, 0, 0);
    }
  }
  const int c = l & 15;
  #pragma unroll
  for(int j=0;j<4;++j){
    int T = Tb + j;
    int n = (c&3)*800 + T*4 + (c>>2);
    float bias = bih[n] + bhh[n];
    h4 o;
    o[0]=(_Float16)(acc[j][0]+bias); o[1]=(_Float16)(acc[j][1]+bias);
    o[2]=(_Float16)(acc[j][2]+bias); o[3]=(_Float16)(acc[j][3]+bias);
    *(h4*)(Gp + (((size_t)mt*NT + T)*64 + l)*4) = o;
  }
}

// ---------------- persistent LSTM layer (fence-free LLC sync) ----------------
// 100 blocks x 256 threads (4 waves, 1 tile each). Blocks 0..49 fwd, 50..99 bwd.
// h stored globally in A-fragment layout: h[t*3200 + dir*1600 + q*64+sub*16+m].
// Staging = contiguous 25.6KB copy; LDS image XOR-swizzled. Per-block monotone
// flag words (plain sc1 stores), all waves poll in parallel.
__global__ __launch_bounds__(256,1) void lstm_kernel(
  const h8* __restrict__ WpF, const h8* __restrict__ WpB,
  const _Float16* __restrict__ GpF, const _Float16* __restrict__ GpB,
  h8* __restrict__ hfrag, int* __restrict__ flags)
{
  __shared__ h8 sh[1600];   // h_prev tile, swizzled (25.6 KB)
  const int tid = threadIdx.x;
  const int wv  = tid >> 6;
  const int l   = tid & 63;
  const bool bwd = blockIdx.x >= LBLK;
  const int bd  = bwd ? (int)blockIdx.x - LBLK : (int)blockIdx.x;  // 0..49
  const int T   = bd*4 + wv;                                       // 0..199
  const h8* Wp = bwd ? WpB : WpF;
  const _Float16* Gp = bwd ? GpB : GpF;
  const int dirOff = bwd ? 1600 : 0;
  int* flg = flags + (bwd ? 64 : 0);

  h8 Bf[KQ_HH];
  #pragma unroll
  for(int q=0;q<KQ_HH;++q) Bf[q] = Wp[(T*KQ_HH + q)*64 + l];

  float cs[4] = {0.f,0.f,0.f,0.f};
  const int lb = l & ~3;
  const int rbase = l ^ ((l>>3)&6);            // swizzled LDS read base
  const int qT = T>>3, subT = (T&7)>>1, halfT = T&1;

  for(int s=0; s<L_SEQ; ++s){
    const int t = bwd ? (L_SEQ-1-s) : s;

    // prefetch Gp[t] before the poll (lands during the wait)
    h4 gp4 = *(const h4*)(Gp + (((size_t)t*NT + T)*64 + l)*4);

    #pragma unroll
    for(int q=0;q<KQ_HH;++q) asm volatile("" : "+v"(Bf[q]));   // keep resident

    if(s > 0){
      // all-lane parallel poll: lane b<50 watches block b's monotone counter
      unsigned long long fa = (unsigned long long)(flg + (l < LBLK ? l : 0));
      int v;
      for(;;){
        asm volatile("global_load_dword %0, %1, off sc1\n\ts_waitcnt vmcnt(0)"
                     : "=v"(v) : "v"(fa) : "memory");
        if(__all(l >= LBLK || v >= s)) break;
        __builtin_amdgcn_s_sleep(1);
      }
      // contiguous coalesced staging of h[t_prev] (own direction, 1600 units)
      const h8* src = hfrag + (size_t)(bwd ? t+1 : t-1)*3200 + dirOff;
      v4i w[7];
      #pragma unroll
      for(int c=0;c<6;++c){
        unsigned long long ad = (unsigned long long)(src + tid + 256*c);
        asm volatile("global_load_dwordx4 %0, %1, off sc1" : "=v"(w[c]) : "v"(ad) : "memory");
      }
      if(tid < 64){
        unsigned long long ad = (unsigned long long)(src + 1536 + tid);
        asm volatile("global_load_dwordx4 %0, %1, off sc1" : "=v"(w[6]) : "v"(ad) : "memory");
      }
      asm volatile("s_waitcnt vmcnt(0)" ::: "memory");
      #pragma unroll
      for(int c=0;c<6;++c){
        int u = tid + 256*c;
        sh[u ^ ((u>>3)&6)] = __builtin_bit_cast(h8, w[c]);
      }
      if(tid < 64){ int u = 1536 + tid; sh[u ^ ((u>>3)&6)] = __builtin_bit_cast(h8, w[6]); }
      __syncthreads();
    }

    // gates = Gp[t] + h_prev @ W_hh^T
    f4 acc[4];
    acc[0][0]=(float)gp4[0]; acc[0][1]=(float)gp4[1]; acc[0][2]=(float)gp4[2]; acc[0][3]=(float)gp4[3];
    #pragma unroll
    for(int j=1;j<4;++j){ acc[j][0]=0.f; acc[j][1]=0.f; acc[j][2]=0.f; acc[j][3]=0.f; }
    if(s > 0){
      #pragma unroll
      for(int q=0;q<KQ_HH;++q){
        h8 av = sh[q*64 + rbase];
        acc[q&3] = __builtin_amdgcn_mfma_f32_16x16x32_f16(av, Bf[q], acc[q&3], 0,0,0);
      }
    }
    f4 g = (acc[0]+acc[1]) + (acc[2]+acc[3]);

    float hv[4];
    #pragma unroll
    for(int r=0;r<4;++r){
      float iv = __shfl(g[r], lb+0, 64);
      float fv = __shfl(g[r], lb+1, 64);
      float gv = __shfl(g[r], lb+2, 64);
      float ov = __shfl(g[r], lb+3, 64);
      float cn = sigmoidf_(fv)*cs[r] + sigmoidf_(iv)*tanhf_(gv);
      cs[r] = cn;
      hv[r] = sigmoidf_(ov)*tanhf_(cn);
    }

    // store h[t] in fragment layout: wave writes 16 x 8B inside a 256B window
    h8* hb = hfrag + (size_t)t*3200 + dirOff + qT*64 + subT*16;
    #pragma unroll
    for(int r=0;r<4;++r){
      const int srcl = (l&3) << 4;
      float v0 = __shfl(hv[r], srcl+0, 64);
      float v1 = __shfl(hv[r], srcl+4, 64);
      float v2 = __shfl(hv[r], srcl+8, 64);
      float v3 = __shfl(hv[r], srcl+12, 64);
      if((l >> 2) == r){
        h4 o; o[0]=(_Float16)v0; o[1]=(_Float16)v1; o[2]=(_Float16)v2; o[3]=(_Float16)v3;
        int mrow = (l&3)*4 + r;
        unsigned long long ad = (unsigned long long)((char*)(hb + mrow) + halfT*8);
        v2i ov = __builtin_bit_cast(v2i, o);
        asm volatile("global_store_dwordx2 %0, %1, off sc1" : : "v"(ad), "v"(ov) : "memory");
      }
    }
    asm volatile("s_waitcnt vmcnt(0)" : : : "memory");   // stores acked at LLC
    __syncthreads();                                      // whole block done
    if(tid == 0 && s != L_SEQ-1){
      int val = s + 1;
      unsigned long long fa2 = (unsigned long long)(flg + bd);
      asm volatile("global_store_dword %0, %1, off sc1" : : "v"(fa2), "v"(val) : "memory");
    }
  }
}

// ---------------- head: fc -> softmax-free atan2 -> SRF ---------------------
// h1 arrives in fragment layout; de-permute into LDS (batch-major) then dot.
__global__ void head_kernel(const h8* __restrict__ h1f,
                            const float* __restrict__ fcw, const float* __restrict__ fcb,
                            const float* __restrict__ alphabet,
                            const float* __restrict__ bl, const float* __restrict__ ba,
                            float* __restrict__ srf)
{
  __shared__ h8 sh8[16*201];   // stride 201 units (3216B = 804 words, %32=4)
  __shared__ float slog[960];
  __shared__ float smax[16];
  __shared__ float sphi[48];
  const int t = blockIdx.x, tid = threadIdx.x;
  const h8* src = h1f + (size_t)t*3200;
  for(int u=tid; u<3200; u+=256){
    int q2 = u >> 6, r = u & 63, sub = r >> 4, m = r & 15;
    sh8[m*201 + (q2<<2) + sub] = src[u];
  }
  __syncthreads();
  for(int it=tid; it<960; it+=256){
    int j = it >> 4, b = it & 15;
    float acc = fcb[j];
    const float4* wr = (const float4*)(fcw + (size_t)j*1600);
    const h8* hr = sh8 + b*201;
    for(int k=0;k<200;++k){
      h8 hv = hr[k];
      float4 w0 = wr[2*k], w1 = wr[2*k+1];
      acc += w0.x*(float)hv[0] + w0.y*(float)hv[1] + w0.z*(float)hv[2] + w0.w*(float)hv[3]
           + w1.x*(float)hv[4] + w1.y*(float)hv[5] + w1.z*(float)hv[6] + w1.w*(float)hv[7];
    }
    slog[b*60 + j] = acc;
  }
  __syncthreads();
  if(tid < 16){
    float mx = -1e30f;
    for(int j=0;j<60;++j) mx = fmaxf(mx, slog[tid*60+j]);
    smax[tid] = mx;
  }
  __syncthreads();
  if(tid < 48){
    int b = tid/3, ax = tid%3;
    float s=0.f, c=0.f, mx = smax[b];
    for(int j=0;j<60;++j){
      float e = __expf(slog[b*60+j] - mx);
      float al = alphabet[j*3 + ax];
      s += e*__sinf(al); c += e*__cosf(al);
    }
    sphi[b*3+ax] = atan2f(s, c);   // softmax denominator cancels in atan2
  }
  __syncthreads();
  if(tid < 144){
    int jj = tid/48; int r_ = tid%48; int b = r_/3, ax = r_%3;
    float rr = bl[jj], th = ba[jj], ph = sphi[b*3+jj];
    float v = (ax==0) ? rr*__cosf(th)
            : (ax==1) ? rr*__cosf(ph)*__sinf(th)
                      : rr*__sinf(ph)*__sinf(th);
    srf[(((size_t)(3*t+jj))*16 + b)*3 + ax] = v;
  }
}

// ---------------- pNeRF: 384 chain scans + 23 fragment stitches -------------
__device__ __forceinline__ void frame_cols(
  float ax,float ay,float az, float bx,float by,float bz, float cx,float cy,float cz,
  float* R)
{
  float ux=cx-bx, uy=cy-by, uz=cz-bz;
  float ir = rsqrtf(ux*ux+uy*uy+uz*uz);
  float bcx=ux*ir, bcy=uy*ir, bcz=uz*ir;
  float px=bx-ax, py=by-ay, pz=bz-az;
  float nx=py*bcz-pz*bcy, ny=pz*bcx-px*bcz, nz=px*bcy-py*bcx;
  float in_ = rsqrtf(nx*nx+ny*ny+nz*nz);
  nx*=in_; ny*=in_; nz*=in_;
  float mx=ny*bcz-nz*bcy, my=nz*bcx-nx*bcz, mz=nx*bcy-ny*bcx;
  R[0]=bcx;R[1]=bcy;R[2]=bcz; R[3]=mx;R[4]=my;R[5]=mz; R[6]=nx;R[7]=ny;R[8]=nz;
}

__global__ void pnerf_kernel(const float* __restrict__ srf,
                             float* __restrict__ frag, float* __restrict__ out)
{
  __shared__ float tail[3][16][3];
  __shared__ float sR[16][9];
  __shared__ float sorg[16][3];
  const int tid = threadIdx.x;
  if(tid < 384){
    int k = tid >> 4, b = tid & 15;
    float ax=-0.70710678f, ay=1.22474487f, az=0.f;
    float bx=-1.41421356f, by=0.f, bz=0.f;
    float cx=0.f, cy=0.f, cz=0.f;
    for(int f=0; f<72; ++f){
      const float* ct = srf + (((size_t)(k*72+f))*16 + b)*3;
      float t0=ct[0], t1=ct[1], t2=ct[2];
      float R[9];
      frame_cols(ax,ay,az, bx,by,bz, cx,cy,cz, R);
      float dx = cx + R[0]*t0 + R[3]*t1 + R[6]*t2;
      float dy = cy + R[1]*t0 + R[4]*t1 + R[7]*t2;
      float dz = cz + R[2]*t0 + R[5]*t1 + R[8]*t2;
      float* fr = frag + (((size_t)(f*24+k))*16 + b)*3;
      fr[0]=dx; fr[1]=dy; fr[2]=dz;
      if(k == 0){
        float* o = out + ((size_t)(f*16)+b)*3;
        o[0]=dx; o[1]=dy; o[2]=dz;
        if(f >= 69){ tail[f-69][b][0]=dx; tail[f-69][b][1]=dy; tail[f-69][b][2]=dz; }
      }
      ax=bx; ay=by; az=bz;  bx=cx; by=cy; bz=cz;  cx=dx; cy=dy; cz=dz;
    }
  }
  __syncthreads();
  for(int kk=1; kk<24; ++kk){
    if(tid < 16){
      int b = tid;
      frame_cols(tail[0][b][0],tail[0][b][1],tail[0][b][2],
                 tail[1][b][0],tail[1][b][1],tail[1][b][2],
                 tail[2][b][0],tail[2][b][1],tail[2][b][2], &sR[b][0]);
      sorg[b][0]=tail[2][b][0]; sorg[b][1]=tail[2][b][1]; sorg[b][2]=tail[2][b][2];
    }
    __syncthreads();
    for(int idx=tid; idx<1152; idx+=blockDim.x){
      int f = idx >> 4, b = idx & 15;
      const float* v = frag + (((size_t)(f*24+kk))*16 + b)*3;
      float vx=v[0], vy=v[1], vz=v[2];
      float gx = sorg[b][0] + sR[b][0]*vx + sR[b][3]*vy + sR[b][6]*vz;
      float gy = sorg[b][1] + sR[b][1]*vx + sR[b][4]*vy + sR[b][7]*vz;
      float gz = sorg[b][2] + sR[b][2]*vx + sR[b][5]*vy + sR[b][8]*vz;
      float* o = out + (((size_t)(kk*72+f))*16 + b)*3;
      o[0]=gx; o[1]=gy; o[2]=gz;
      if(f >= 69){ tail[f-69][b][0]=gx; tail[f-69][b][1]=gy; tail[f-69][b][2]=gz; }
    }
    __syncthreads();
  }
}

// ---------------------------------------------------------------------------
extern "C" void kernel_launch(void* const* d_in, const int* in_sizes, int n_in,
                              void* d_out, int out_size, void* d_ws, size_t ws_size,
                              hipStream_t stream)
{
  (void)in_sizes; (void)n_in; (void)out_size; (void)ws_size;
  const int*   seq  = (const int*)d_in[0];
  const float* pssm = (const float*)d_in[1];
  const float* w_ih_l0f=(const float*)d_in[3];  const float* w_hh_l0f=(const float*)d_in[4];
  const float* b_ih_l0f=(const float*)d_in[5];  const float* b_hh_l0f=(const float*)d_in[6];
  const float* w_ih_l0b=(const float*)d_in[7];  const float* w_hh_l0b=(const float*)d_in[8];
  const float* b_ih_l0b=(const float*)d_in[9];  const float* b_hh_l0b=(const float*)d_in[10];
  const float* w_ih_l1f=(const float*)d_in[11]; const float* w_hh_l1f=(const float*)d_in[12];
  const float* b_ih_l1f=(const float*)d_in[13]; const float* b_hh_l1f=(const float*)d_in[14];
  const float* w_ih_l1b=(const float*)d_in[15]; const float* w_hh_l1b=(const float*)d_in[16];
  const float* b_ih_l1b=(const float*)d_in[17]; const float* b_hh_l1b=(const float*)d_in[18];
  const float* fc_w=(const float*)d_in[19];     const float* fc_b=(const float*)d_in[20];
  const float* alphabet=(const float*)d_in[21];
  const float* bl=(const float*)d_in[22];       const float* ba=(const float*)d_in[23];
  float* out = (float*)d_out;

  char* ws = (char*)d_ws;
  size_t o = 0;
  auto alloc = [&](size_t bytes){ size_t r = o; o = (o + bytes + 255) & ~(size_t)255; return r; };
  size_t o_wphh = alloc(4ull*320000*16);   // 20.48 MB  W_hh frags (4 dirs)
  size_t o_wp1  = alloc(2ull*640000*16);   // 20.48 MB  W_ih_l1 frags
  size_t o_wp0  = alloc(2ull*25600*16);    //  0.82 MB  W_ih_l0 frags (padded K=64)
  size_t o_gpf  = alloc(2ull*29491200);    // 58.98 MB  Gp fwd
  size_t o_gpb  = alloc(2ull*29491200);    // 58.98 MB  Gp bwd
  size_t o_h0   = alloc(16ull*576*3200);   // 29.49 MB  h0 frag layout (h8 units)
  size_t o_h1   = alloc(16ull*576*3200);   // 29.49 MB  h1 frag layout
  size_t o_x    = alloc(2ull*589824);      //  1.18 MB  x f16 (9216,64)
  size_t o_srf  = alloc(4ull*82944);       //  SRF
  size_t o_frag = alloc(4ull*82944);       //  pnerf fragments
  size_t o_flag = alloc(4ull*256);         //  flags: 4 regions x 64 words

  h8* wp_hh = (h8*)(ws + o_wphh);
  h8* wp1   = (h8*)(ws + o_wp1);
  h8* wp0   = (h8*)(ws + o_wp0);
  _Float16* gpf = (_Float16*)(ws + o_gpf);
  _Float16* gpb = (_Float16*)(ws + o_gpb);
  h8* h0    = (h8*)(ws + o_h0);
  h8* h1    = (h8*)(ws + o_h1);
  _Float16* x = (_Float16*)(ws + o_x);
  float* srf    = (float*)(ws + o_srf);
  float* frag   = (float*)(ws + o_frag);
  int* flags    = (int*)(ws + o_flag);

  init_kernel<<<1, 256, 0, stream>>>(flags);
  build_x<<<2304, 256, 0, stream>>>(seq, pssm, x);
  prep_w<<<10200, 256, 0, stream>>>(w_hh_l0f, w_hh_l0b, w_hh_l1f, w_hh_l1b,
                                    w_ih_l1f, w_ih_l1b, w_ih_l0f, w_ih_l0b,
                                    wp_hh, wp1, wp0);
  // layer 0 input projection
  gemm_l0<<<14400, 256, 0, stream>>>(x, wp0, wp0 + 25600,
                                     b_ih_l0f, b_hh_l0f, b_ih_l0b, b_hh_l0b, gpf, gpb);
  // layer 0 recurrence
  lstm_kernel<<<100, 256, 0, stream>>>(wp_hh, wp_hh + 320000, gpf, gpb, h0, flags);
  // layer 1 input projection (h0 fragment layout, K=1600 contiguous)
  gemm_l1<<<14400, 256, 0, stream>>>(h0, wp1, wp1 + 640000,
                                     b_ih_l1f, b_hh_l1f, b_ih_l1b, b_hh_l1b, gpf, gpb);
  // layer 1 recurrence (separate flag region)
  lstm_kernel<<<100, 256, 0, stream>>>(wp_hh + 640000, wp_hh + 960000, gpf, gpb, h1,
                                       flags + 128);
  // fc head -> torsions -> SRF
  head_kernel<<<576, 256, 0, stream>>>(h1, fc_w, fc_b, alphabet, bl, ba, srf);
  // geometric chain
  pnerf_kernel<<<1, 512, 0, stream>>>(srf, frag, out);
}